// Round 8
// baseline (180.840 us; speedup 1.0000x reference)
//
#include <hip/hip_runtime.h>

#define T   512
#define B   512
#define NT  64
#define QS  16            // steps per staging quarter
#define NQ  (T / QS)      // 32 quarters total
#define FNQ 16            // fwd quarters 0..15  (steps 1..255)
#define RING 4            // LDS ring: 4 quarters = 64 rows, lead distance 3

typedef _Float16 h2 __attribute__((ext_vector_type(2)));

__device__ __forceinline__ float rflf(float x) {
    return __uint_as_float(__builtin_amdgcn_readfirstlane(__float_as_uint(x)));
}
__device__ __forceinline__ float dot2(h2 a, h2 b, float c) {
#if __has_builtin(__builtin_amdgcn_fdot2)
    return __builtin_amdgcn_fdot2(a, b, c, false);
#else
    return c + (float)a.x * (float)b.x + (float)a.y * (float)b.y;
#endif
}
__device__ __forceinline__ h2  bch2(int u) { return __builtin_bit_cast(h2, u); }
__device__ __forceinline__ int cvtpk(float a, float b) {
    return __builtin_bit_cast(int, __builtin_amdgcn_cvt_pkrtz(a, b));
}

// ---------------------------------------------------------------------------
// Round 8: round 7 validated the fwd/bwd split (depth 511 -> 256, 112 -> 74 us
// dispatch; depth T/2 is optimal for vector propagation). This round fuses
// everything into ONE kernel: each chain block holds 128 threads -- wave 0
// runs the forward half (steps 1..255), wave 1 the backward half (steps
// 511..256) -- with separate LDS staging rings. The combine (dot + log) is
// done in-block after __syncthreads, removing the crf_comb launch, the
// workspace round-trip, and one dispatch of graph overhead. Chain bodies are
// the round-3/7 verified ones, bit-identical math and reduction order.
// Numerator blocks (B..B+255) run 2 batches each (one per wave).
// ---------------------------------------------------------------------------
__global__ __launch_bounds__(128) void crf_all(
    const float* __restrict__ emissions,  // [T, B, NT]
    const int*   __restrict__ tags,       // [T, B]
    const int*   __restrict__ mask,       // [T, B]
    const float* __restrict__ startT,     // [NT]
    const float* __restrict__ endT,       // [NT]
    const float* __restrict__ trans,      // [NT, NT]
    float* __restrict__ out)
{
    const int wid = threadIdx.x >> 6;
    const int j   = threadIdx.x & 63;

    __shared__ __align__(16) float ebuf2[2][RING][QS][NT];  // 32 KB
    __shared__ float qx[NT];     // bwd result vector
    __shared__ float sbb;        // bwd scalar  Kb*ln2

    if (blockIdx.x < B) {
        // ===================== chain block, batch b =========================
        const int b = blockIdx.x;
        float (*ebuf)[QS][NT] = ebuf2[wid];
        float* eflat = &ebuf[0][0][0];

        const int jr = j >> 4;
        const int c0 = (j & 15) * 4;
        float4 sA[4];
        auto issue_q = [&](int g) {
#pragma unroll
            for (int k = 0; k < 4; ++k) {
                const int t = g * QS + 4 * k + jr;
                sA[k] = *(const float4*)&emissions[((size_t)t * B + b) * NT + c0];
            }
        };
        auto write_q = [&](int g) {
#pragma unroll
            for (int k = 0; k < 4; ++k) {
                float4 w;
                w.x = __expf(sA[k].x); w.y = __expf(sA[k].y);
                w.z = __expf(sA[k].z); w.w = __expf(sA[k].w);
                *(float4*)&ebuf[g & (RING - 1)][4 * k + jr][c0] = w;
            }
        };

        float qf_final = 0.f, sf_final = 0.f;

        if (wid == 0) {
            // ---------------- forward half, steps 1..255 --------------------
            h2 Eh[NT / 2];                    // E column-j pairs over i
#pragma unroll
            for (int m = 0; m < NT / 2; ++m) {
                Eh[m].x = (_Float16)__expf(trans[(2 * m)     * NT + j]);
                Eh[m].y = (_Float16)__expf(trans[(2 * m + 1) * NT + j]);
            }

            for (int g = 0; g < 3; ++g) { issue_q(g); write_q(g); }
            issue_q(3);

            const float e0  = emissions[(size_t)b * NT + j];
            const float sc0 = startT[j] + e0;
            const float S0  = rflf(sc0);
            float q = __expf(sc0 - S0);
            int   K = 0;
            int pk_i;
            {
                const int qi = __float_as_int(q);
                const int qo = __builtin_amdgcn_update_dpp(0, qi, 0xB1, 0xF, 0xF, true);
                pk_i = cvtpk(q, __int_as_float(qo));
            }
            int bits_prev;
            int mpre = mask[j * B + b];
            unsigned long long mbc = 0;

            {   // peeled step 1 (prompt renorm)
                int u[32];
#pragma unroll
                for (int m = 0; m < 32; ++m) u[m] = __builtin_amdgcn_readlane(pk_i, 2 * m);
                float a[8] = {0.f,0.f,0.f,0.f,0.f,0.f,0.f,0.f};
#pragma unroll
                for (int m = 0; m < 32; ++m) a[m & 7] = dot2(bch2(u[m]), Eh[m], a[m & 7]);
                const float p = ((a[0]+a[1])+(a[2]+a[3])) + ((a[4]+a[5])+(a[6]+a[7]));
                bits_prev = __builtin_amdgcn_readfirstlane(__float_as_int(p));
                const int  k = ((bits_prev >> 23) & 255) - 127;
                const float r = __int_as_float((125 - k) << 23);
                const float X1 = eflat[NT + j];
                const int  m1 = mask[B + b];
                if (m1) { q = (p * X1) * r; K = k + 2; }
                const int qo = __builtin_amdgcn_update_dpp(0, __float_as_int(q), 0xB1, 0xF, 0xF, true);
                pk_i = cvtpk(q, __int_as_float(qo));
            }
            float Xc = eflat[2 * NT + j];
            float Xn = eflat[3 * NT + j];

            auto stepF = [&](int s) {
                int u[32];
#pragma unroll
                for (int m = 0; m < 32; ++m) u[m] = __builtin_amdgcn_readlane(pk_i, 2 * m);
                __builtin_amdgcn_sched_barrier(0);
                const int  k = ((bits_prev >> 23) & 255) - 127;
                const float r = __int_as_float((125 - k) << 23);
                K += k + 2;
                float a[8] = {0.f,0.f,0.f,0.f,0.f,0.f,0.f,0.f};
#pragma unroll
                for (int m = 0; m < 32; ++m) a[m & 7] = dot2(bch2(u[m]), Eh[m], a[m & 7]);
                const float sXr = Xc * r;
                const float p = ((a[0]+a[1])+(a[2]+a[3])) + ((a[4]+a[5])+(a[6]+a[7]));
                q = p * sXr;
                bits_prev = __builtin_amdgcn_readfirstlane(__float_as_int(p));
                const int qo = __builtin_amdgcn_update_dpp(0, __float_as_int(q), 0xB1, 0xF, 0xF, true);
                pk_i = cvtpk(q, __int_as_float(qo));
                Xc = Xn;
                Xn = eflat[((s + 2) & 63) * NT + j];
            };
            auto stepM = [&](int s) {
                int u[32];
#pragma unroll
                for (int m = 0; m < 32; ++m) u[m] = __builtin_amdgcn_readlane(pk_i, 2 * m);
                __builtin_amdgcn_sched_barrier(0);
                const int  k = ((bits_prev >> 23) & 255) - 127;
                const float r = __int_as_float((125 - k) << 23);
                const bool mc = (mbc >> (s & 63)) & 1ull;
                const float mf = mc ? 1.0f : 0.0f;
                K += mc ? (k + 2) : 0;
                float a[8] = {0.f,0.f,0.f,0.f,0.f,0.f,0.f,0.f};
#pragma unroll
                for (int m = 0; m < 32; ++m) a[m & 7] = dot2(bch2(u[m]), Eh[m], a[m & 7]);
                const float sXr = Xc * r;
                const float p = ((a[0]+a[1])+(a[2]+a[3])) + ((a[4]+a[5])+(a[6]+a[7]));
                const float qn = p * sXr;
                q = fmaf(mf, qn - q, q);
                bits_prev = __builtin_amdgcn_readfirstlane(__float_as_int(p));
                const int qo = __builtin_amdgcn_update_dpp(0, __float_as_int(q), 0xB1, 0xF, 0xF, true);
                pk_i = cvtpk(q, __int_as_float(qo));
                Xc = Xn;
                Xn = eflat[((s + 2) & 63) * NT + j];
            };

            for (int x = 0; x < FNQ; ++x) {
                const int gw = (x + 3 < FNQ) ? x + 3 : FNQ - 1;
                write_q(gw);
                const int gl = (x + 4 < FNQ) ? x + 4 : FNQ - 1;
                issue_q(gl);
                if ((x & 3) == 0) {
                    mbc = __ballot(mpre != 0);
                    const int cn = ((x >> 2) + 1 < 4) ? (x >> 2) + 1 : 3;
                    mpre = mask[(cn * 64 + j) * B + b];
                }
                const unsigned qb16 = (unsigned)(mbc >> ((x & 3) << 4)) & 0xFFFFu;
                const int tt0 = (x == 0) ? 2 : 0;
                if (qb16 == 0xFFFFu) {
#pragma unroll 1
                    for (int tt = tt0; tt < QS; ++tt) stepF(x * QS + tt);
                } else {
#pragma unroll 1
                    for (int tt = tt0; tt < QS; ++tt) stepM(x * QS + tt);
                }
            }
            qf_final = q;
            sf_final = S0 + (float)K * 0.69314718f;

        } else {
            // ---------------- backward half, steps 511..256 -----------------
            h2 Er[NT / 2];                    // E ROW-j pairs over i
#pragma unroll
            for (int m = 0; m < NT / 2; ++m) {
                Er[m].x = (_Float16)__expf(trans[j * NT + 2 * m]);
                Er[m].y = (_Float16)__expf(trans[j * NT + 2 * m + 1]);
            }

            for (int g = 31; g > 28; --g) { issue_q(g); write_q(g); }
            issue_q(28);

            float v = __expf(endT[j]);
            int   K = 0;
            int bits_prev;
            int mpre = mask[(7 * 64 + j) * B + b];   // chunk-7 mask column
            unsigned long long mbc = 0;
            int pk_i;
            {   // pack y = v * X_511 for the peeled step
                const float y  = v * eflat[63 * NT + j];
                const int  yo = __builtin_amdgcn_update_dpp(0, __float_as_int(y), 0xB1, 0xF, 0xF, true);
                pk_i = cvtpk(y, __int_as_float(yo));
            }
            {   // peeled step 511 (prompt renorm)
                int u[32];
#pragma unroll
                for (int m = 0; m < 32; ++m) u[m] = __builtin_amdgcn_readlane(pk_i, 2 * m);
                float a[8] = {0.f,0.f,0.f,0.f,0.f,0.f,0.f,0.f};
#pragma unroll
                for (int m = 0; m < 32; ++m) a[m & 7] = dot2(bch2(u[m]), Er[m], a[m & 7]);
                const float p = ((a[0]+a[1])+(a[2]+a[3])) + ((a[4]+a[5])+(a[6]+a[7]));
                bits_prev = __builtin_amdgcn_readfirstlane(__float_as_int(p));
                const int  k = ((bits_prev >> 23) & 255) - 127;
                const float r = __int_as_float((125 - k) << 23);
                const int  m511 = mask[511 * B + b];
                if (m511) { v = p * r; K = k + 2; }
                const float y  = v * eflat[62 * NT + j];   // X_510
                const int  yo = __builtin_amdgcn_update_dpp(0, __float_as_int(y), 0xB1, 0xF, 0xF, true);
                pk_i = cvtpk(y, __int_as_float(yo));
            }

            auto bstepF = [&](int s) {
                int u[32];
#pragma unroll
                for (int m = 0; m < 32; ++m) u[m] = __builtin_amdgcn_readlane(pk_i, 2 * m);
                __builtin_amdgcn_sched_barrier(0);
                const int  k = ((bits_prev >> 23) & 255) - 127;
                const float r = __int_as_float((125 - k) << 23);
                K += k + 2;
                float a[8] = {0.f,0.f,0.f,0.f,0.f,0.f,0.f,0.f};
#pragma unroll
                for (int m = 0; m < 32; ++m) a[m & 7] = dot2(bch2(u[m]), Er[m], a[m & 7]);
                const float Xn = eflat[((s - 1) & 63) * NT + j];
                const float p = ((a[0]+a[1])+(a[2]+a[3])) + ((a[4]+a[5])+(a[6]+a[7]));
                v = p * r;
                bits_prev = __builtin_amdgcn_readfirstlane(__float_as_int(p));
                const float y  = v * Xn;
                const int  yo = __builtin_amdgcn_update_dpp(0, __float_as_int(y), 0xB1, 0xF, 0xF, true);
                pk_i = cvtpk(y, __int_as_float(yo));
            };
            auto bstepM = [&](int s) {
                int u[32];
#pragma unroll
                for (int m = 0; m < 32; ++m) u[m] = __builtin_amdgcn_readlane(pk_i, 2 * m);
                __builtin_amdgcn_sched_barrier(0);
                const int  k = ((bits_prev >> 23) & 255) - 127;
                const float r = __int_as_float((125 - k) << 23);
                const bool mc = (mbc >> (s & 63)) & 1ull;
                const float mf = mc ? 1.0f : 0.0f;
                K += mc ? (k + 2) : 0;
                float a[8] = {0.f,0.f,0.f,0.f,0.f,0.f,0.f,0.f};
#pragma unroll
                for (int m = 0; m < 32; ++m) a[m & 7] = dot2(bch2(u[m]), Er[m], a[m & 7]);
                const float Xn = eflat[((s - 1) & 63) * NT + j];
                const float p = ((a[0]+a[1])+(a[2]+a[3])) + ((a[4]+a[5])+(a[6]+a[7]));
                const float vn = p * r;
                v = fmaf(mf, vn - v, v);
                bits_prev = __builtin_amdgcn_readfirstlane(__float_as_int(p));
                const float y  = v * Xn;
                const int  yo = __builtin_amdgcn_update_dpp(0, __float_as_int(y), 0xB1, 0xF, 0xF, true);
                pk_i = cvtpk(y, __int_as_float(yo));
            };

            for (int x = NQ - 1; x >= 16; --x) {
                const int gw = (x - 3 >= 16) ? x - 3 : 16;
                write_q(gw);
                const int gl = (x - 4 >= 16) ? x - 4 : 16;
                issue_q(gl);
                if ((x & 3) == 3) {
                    mbc = __ballot(mpre != 0);
                    const int cn = ((x >> 2) - 1 > 4) ? (x >> 2) - 1 : 4;
                    mpre = mask[(cn * 64 + j) * B + b];
                }
                const unsigned qb16 = (unsigned)(mbc >> ((x & 3) << 4)) & 0xFFFFu;
                const int tts = (x == NQ - 1) ? QS - 2 : QS - 1;
                if (qb16 == 0xFFFFu) {
#pragma unroll 1
                    for (int tt = tts; tt >= 0; --tt) bstepF(x * QS + tt);
                } else {
#pragma unroll 1
                    for (int tt = tts; tt >= 0; --tt) bstepM(x * QS + tt);
                }
            }
            qx[j] = v;
            if (j == 0) sbb = (float)K * 0.69314718f;
        }

        __syncthreads();

        if (wid == 0) {
            // den_b = sf + sb + log( sum_j qf_j * qb_j )
            float v = qf_final * qx[j];
#pragma unroll
            for (int off = 32; off > 0; off >>= 1)
                v += __shfl_xor(v, off);
            if (j == 0)
                atomicAdd(out, -(sf_final + sbb + __logf(v)));
        }

    } else {
        // =================== numerator, 2 batches / block ===================
        const int b = (blockIdx.x - B) * 2 + wid;
        float acc = 0.f;
        int   cnt = 0;
#pragma unroll
        for (int m = 0; m < T / 64; ++m) {
            const int t  = j + 64 * m;
            const int mv = mask[t * B + b];
            const int tg = tags[t * B + b];
            cnt += (int)__popcll(__ballot(mv != 0));
            if (t == 0) {
                acc += startT[tg] + emissions[(size_t)b * NT + tg];
            } else if (mv) {
                const int tp = tags[(t - 1) * B + b];
                acc += trans[tp * NT + tg]
                     + emissions[(size_t)(t * B + b) * NT + tg];
            }
        }
#pragma unroll
        for (int off = 32; off > 0; off >>= 1)
            acc += __shfl_xor(acc, off);
        if (j == 0) {
            const int last = tags[(size_t)(cnt - 1) * B + b];
            atomicAdd(out, acc + endT[last]);
        }
    }
}

extern "C" void kernel_launch(void* const* d_in, const int* in_sizes, int n_in,
                              void* d_out, int out_size, void* d_ws, size_t ws_size,
                              hipStream_t stream) {
    const float* emissions = (const float*)d_in[0];
    const int*   tags      = (const int*)  d_in[1];
    const int*   mask      = (const int*)  d_in[2];
    const float* startT    = (const float*)d_in[3];
    const float* endT      = (const float*)d_in[4];
    const float* trans     = (const float*)d_in[5];
    float* out = (float*)d_out;

    hipMemsetAsync(out, 0, sizeof(float), stream);
    crf_all<<<B + B / 2, 128, 0, stream>>>(
        emissions, tags, mask, startT, endT, trans, out);
}

// Round 9
// 156.294 us; speedup vs baseline: 1.1571x; 1.1571x over previous
//
#include <hip/hip_runtime.h>

#define T   512
#define B   512
#define NT  64
#define QS  16            // steps per staging quarter
#define NQ  (T / QS)      // 32 quarters total
#define FNQ 16            // fwd quarters 0..15  (steps 1..255)
#define RING 4            // LDS ring: 4 quarters = 64 rows, lead distance 3

typedef _Float16 h2 __attribute__((ext_vector_type(2)));

__device__ __forceinline__ float rflf(float x) {
    return __uint_as_float(__builtin_amdgcn_readfirstlane(__float_as_uint(x)));
}
__device__ __forceinline__ float dot2(h2 a, h2 b, float c) {
#if __has_builtin(__builtin_amdgcn_fdot2)
    return __builtin_amdgcn_fdot2(a, b, c, false);
#else
    return c + (float)a.x * (float)b.x + (float)a.y * (float)b.y;
#endif
}
__device__ __forceinline__ h2  bch2(int u) { return __builtin_bit_cast(h2, u); }
__device__ __forceinline__ int cvtpk(float a, float b) {
    return __builtin_bit_cast(int, __builtin_amdgcn_cvt_pkrtz(a, b));
}

// ---------------------------------------------------------------------------
// Round 9: round-7 structure (separate fwd/bwd/numerator blocks — round 8's
// same-CU fusion cost 33%/step, reverted) with the bwd chain shortened to
// match fwd:
//   - Xc/Xn register pipeline one full step ahead (the old in-step ds_read
//     of the pack multiplier put ~120cy of LDS latency on the serial chain),
//   - rX = r*Xc computed off-chain (r lagged, Xc in-register), pack
//     y = p*rX -- ONE on-chain mult, bit-identical since r is a power of 2,
//   - v = p*r kept in the shadow (needed only for masked steps / final).
// Fwd body unchanged (round-3 verified). Combine kernel unchanged.
// ---------------------------------------------------------------------------
__global__ __launch_bounds__(64) void crf_main(
    const float* __restrict__ emissions,  // [T, B, NT]
    const int*   __restrict__ tags,       // [T, B]
    const int*   __restrict__ mask,       // [T, B]
    const float* __restrict__ startT,     // [NT]
    const float* __restrict__ endT,       // [NT]
    const float* __restrict__ trans,      // [NT, NT]
    float* __restrict__ wqf,              // [B][64]
    float* __restrict__ wqb,              // [B][64]
    float* __restrict__ wsf,              // [B]
    float* __restrict__ wsb,              // [B]
    float* __restrict__ out)
{
    const int j = threadIdx.x;
    __shared__ __align__(16) float ebuf[RING][QS][NT];

    if (blockIdx.x < B) {
        // =================== forward half, steps 1..255 =====================
        const int b = blockIdx.x;

        h2 Eh[NT / 2];                    // E column-j pairs over i
#pragma unroll
        for (int m = 0; m < NT / 2; ++m) {
            Eh[m].x = (_Float16)__expf(trans[(2 * m)     * NT + j]);
            Eh[m].y = (_Float16)__expf(trans[(2 * m + 1) * NT + j]);
        }

        const int jr = j >> 4;
        const int c0 = (j & 15) * 4;
        float4 sA[4];
        auto issue_q = [&](int g) {
#pragma unroll
            for (int k = 0; k < 4; ++k) {
                const int t = g * QS + 4 * k + jr;
                sA[k] = *(const float4*)&emissions[((size_t)t * B + b) * NT + c0];
            }
        };
        auto write_q = [&](int g) {
#pragma unroll
            for (int k = 0; k < 4; ++k) {
                float4 w;
                w.x = __expf(sA[k].x); w.y = __expf(sA[k].y);
                w.z = __expf(sA[k].z); w.w = __expf(sA[k].w);
                *(float4*)&ebuf[g & (RING - 1)][4 * k + jr][c0] = w;
            }
        };
        for (int g = 0; g < 3; ++g) { issue_q(g); write_q(g); }
        issue_q(3);

        const float e0  = emissions[(size_t)b * NT + j];
        const float sc0 = startT[j] + e0;
        const float S0  = rflf(sc0);
        float q = __expf(sc0 - S0);
        int   K = 0;
        int pk_i;
        {
            const int qi = __float_as_int(q);
            const int qo = __builtin_amdgcn_update_dpp(0, qi, 0xB1, 0xF, 0xF, true);
            pk_i = cvtpk(q, __int_as_float(qo));
        }
        float* eflat = &ebuf[0][0][0];
        int bits_prev;
        int mpre = mask[j * B + b];
        unsigned long long mbc = 0;

        {   // peeled step 1 (prompt renorm)
            int u[32];
#pragma unroll
            for (int m = 0; m < 32; ++m) u[m] = __builtin_amdgcn_readlane(pk_i, 2 * m);
            float a[8] = {0.f,0.f,0.f,0.f,0.f,0.f,0.f,0.f};
#pragma unroll
            for (int m = 0; m < 32; ++m) a[m & 7] = dot2(bch2(u[m]), Eh[m], a[m & 7]);
            const float p = ((a[0]+a[1])+(a[2]+a[3])) + ((a[4]+a[5])+(a[6]+a[7]));
            bits_prev = __builtin_amdgcn_readfirstlane(__float_as_int(p));
            const int  k = ((bits_prev >> 23) & 255) - 127;
            const float r = __int_as_float((125 - k) << 23);
            const float X1 = eflat[NT + j];
            const int  m1 = mask[B + b];
            if (m1) { q = (p * X1) * r; K = k + 2; }
            const int qo = __builtin_amdgcn_update_dpp(0, __float_as_int(q), 0xB1, 0xF, 0xF, true);
            pk_i = cvtpk(q, __int_as_float(qo));
        }
        float Xc = eflat[2 * NT + j];
        float Xn = eflat[3 * NT + j];

        auto stepF = [&](int s) {
            int u[32];
#pragma unroll
            for (int m = 0; m < 32; ++m) u[m] = __builtin_amdgcn_readlane(pk_i, 2 * m);
            __builtin_amdgcn_sched_barrier(0);
            const int  k = ((bits_prev >> 23) & 255) - 127;
            const float r = __int_as_float((125 - k) << 23);
            K += k + 2;
            float a[8] = {0.f,0.f,0.f,0.f,0.f,0.f,0.f,0.f};
#pragma unroll
            for (int m = 0; m < 32; ++m) a[m & 7] = dot2(bch2(u[m]), Eh[m], a[m & 7]);
            const float sXr = Xc * r;
            const float p = ((a[0]+a[1])+(a[2]+a[3])) + ((a[4]+a[5])+(a[6]+a[7]));
            q = p * sXr;
            bits_prev = __builtin_amdgcn_readfirstlane(__float_as_int(p));
            const int qo = __builtin_amdgcn_update_dpp(0, __float_as_int(q), 0xB1, 0xF, 0xF, true);
            pk_i = cvtpk(q, __int_as_float(qo));
            Xc = Xn;
            Xn = eflat[((s + 2) & 63) * NT + j];
        };
        auto stepM = [&](int s) {
            int u[32];
#pragma unroll
            for (int m = 0; m < 32; ++m) u[m] = __builtin_amdgcn_readlane(pk_i, 2 * m);
            __builtin_amdgcn_sched_barrier(0);
            const int  k = ((bits_prev >> 23) & 255) - 127;
            const float r = __int_as_float((125 - k) << 23);
            const bool mc = (mbc >> (s & 63)) & 1ull;
            const float mf = mc ? 1.0f : 0.0f;
            K += mc ? (k + 2) : 0;
            float a[8] = {0.f,0.f,0.f,0.f,0.f,0.f,0.f,0.f};
#pragma unroll
            for (int m = 0; m < 32; ++m) a[m & 7] = dot2(bch2(u[m]), Eh[m], a[m & 7]);
            const float sXr = Xc * r;
            const float p = ((a[0]+a[1])+(a[2]+a[3])) + ((a[4]+a[5])+(a[6]+a[7]));
            const float qn = p * sXr;
            q = fmaf(mf, qn - q, q);
            bits_prev = __builtin_amdgcn_readfirstlane(__float_as_int(p));
            const int qo = __builtin_amdgcn_update_dpp(0, __float_as_int(q), 0xB1, 0xF, 0xF, true);
            pk_i = cvtpk(q, __int_as_float(qo));
            Xc = Xn;
            Xn = eflat[((s + 2) & 63) * NT + j];
        };

        for (int x = 0; x < FNQ; ++x) {
            const int gw = (x + 3 < FNQ) ? x + 3 : FNQ - 1;
            write_q(gw);
            const int gl = (x + 4 < FNQ) ? x + 4 : FNQ - 1;
            issue_q(gl);
            if ((x & 3) == 0) {
                mbc = __ballot(mpre != 0);
                const int cn = ((x >> 2) + 1 < 4) ? (x >> 2) + 1 : 3;
                mpre = mask[(cn * 64 + j) * B + b];
            }
            const unsigned qb16 = (unsigned)(mbc >> ((x & 3) << 4)) & 0xFFFFu;
            const int tt0 = (x == 0) ? 2 : 0;
            if (qb16 == 0xFFFFu) {
#pragma unroll 1
                for (int tt = tt0; tt < QS; ++tt) stepF(x * QS + tt);
            } else {
#pragma unroll 1
                for (int tt = tt0; tt < QS; ++tt) stepM(x * QS + tt);
            }
        }
        wqf[b * 64 + j] = q;
        if (j == 0) wsf[b] = S0 + (float)K * 0.69314718f;

    } else if (blockIdx.x < 2 * B) {
        // ================== backward half, steps 511..256 ===================
        const int b = blockIdx.x - B;

        h2 Er[NT / 2];                    // E ROW-j pairs over i
#pragma unroll
        for (int m = 0; m < NT / 2; ++m) {
            Er[m].x = (_Float16)__expf(trans[j * NT + 2 * m]);
            Er[m].y = (_Float16)__expf(trans[j * NT + 2 * m + 1]);
        }

        const int jr = j >> 4;
        const int c0 = (j & 15) * 4;
        float4 sA[4];
        auto issue_q = [&](int g) {
#pragma unroll
            for (int k = 0; k < 4; ++k) {
                const int t = g * QS + 4 * k + jr;
                sA[k] = *(const float4*)&emissions[((size_t)t * B + b) * NT + c0];
            }
        };
        auto write_q = [&](int g) {
#pragma unroll
            for (int k = 0; k < 4; ++k) {
                float4 w;
                w.x = __expf(sA[k].x); w.y = __expf(sA[k].y);
                w.z = __expf(sA[k].z); w.w = __expf(sA[k].w);
                *(float4*)&ebuf[g & (RING - 1)][4 * k + jr][c0] = w;
            }
        };
        for (int g = 31; g > 28; --g) { issue_q(g); write_q(g); }
        issue_q(28);

        float v = __expf(endT[j]);
        int   K = 0;
        float* eflat = &ebuf[0][0][0];
        int bits_prev;
        int mpre = mask[(7 * 64 + j) * B + b];   // chunk-7 mask column
        unsigned long long mbc = 0;
        int pk_i;
        {   // pack y = v * X_511 for the peeled step
            const float y  = v * eflat[63 * NT + j];
            const int  yo = __builtin_amdgcn_update_dpp(0, __float_as_int(y), 0xB1, 0xF, 0xF, true);
            pk_i = cvtpk(y, __int_as_float(yo));
        }
        {   // peeled step 511 (prompt renorm)
            int u[32];
#pragma unroll
            for (int m = 0; m < 32; ++m) u[m] = __builtin_amdgcn_readlane(pk_i, 2 * m);
            float a[8] = {0.f,0.f,0.f,0.f,0.f,0.f,0.f,0.f};
#pragma unroll
            for (int m = 0; m < 32; ++m) a[m & 7] = dot2(bch2(u[m]), Er[m], a[m & 7]);
            const float p = ((a[0]+a[1])+(a[2]+a[3])) + ((a[4]+a[5])+(a[6]+a[7]));
            bits_prev = __builtin_amdgcn_readfirstlane(__float_as_int(p));
            const int  k = ((bits_prev >> 23) & 255) - 127;
            const float r = __int_as_float((125 - k) << 23);
            const int  m511 = mask[511 * B + b];
            if (m511) { v = p * r; K = k + 2; }
            const float y  = v * eflat[62 * NT + j];   // X_510 (prompt, one-time)
            const int  yo = __builtin_amdgcn_update_dpp(0, __float_as_int(y), 0xB1, 0xF, 0xF, true);
            pk_i = cvtpk(y, __int_as_float(yo));
        }
        // X register pipeline, one full step ahead (mirror of fwd):
        // at entry to step s: Xc = X_{s-1}, Xn = X_{s-2}
        float Xc = eflat[61 * NT + j];   // X_509
        float Xn = eflat[60 * NT + j];   // X_508

        // step s: consumes pk = pack(v*X_s); chain: p -> y = p*rX -> pack.
        // v = p*r in the shadow (r power-of-2 => (p*r)*X == p*(r*X) exactly).
        auto bstepF = [&](int s) {
            int u[32];
#pragma unroll
            for (int m = 0; m < 32; ++m) u[m] = __builtin_amdgcn_readlane(pk_i, 2 * m);
            __builtin_amdgcn_sched_barrier(0);
            const int  k = ((bits_prev >> 23) & 255) - 127;
            const float r = __int_as_float((125 - k) << 23);
            K += k + 2;
            float a[8] = {0.f,0.f,0.f,0.f,0.f,0.f,0.f,0.f};
#pragma unroll
            for (int m = 0; m < 32; ++m) a[m & 7] = dot2(bch2(u[m]), Er[m], a[m & 7]);
            const float rX = Xc * r;              // off-chain
            const float p = ((a[0]+a[1])+(a[2]+a[3])) + ((a[4]+a[5])+(a[6]+a[7]));
            const float y = p * rX;               // one on-chain mult
            bits_prev = __builtin_amdgcn_readfirstlane(__float_as_int(p));
            const int  yo = __builtin_amdgcn_update_dpp(0, __float_as_int(y), 0xB1, 0xF, 0xF, true);
            pk_i = cvtpk(y, __int_as_float(yo));
            v = p * r;                            // shadow, off-chain
            Xc = Xn;
            Xn = eflat[((s - 3) & 63) * NT + j];
        };
        auto bstepM = [&](int s) {
            int u[32];
#pragma unroll
            for (int m = 0; m < 32; ++m) u[m] = __builtin_amdgcn_readlane(pk_i, 2 * m);
            __builtin_amdgcn_sched_barrier(0);
            const int  k = ((bits_prev >> 23) & 255) - 127;
            const float r = __int_as_float((125 - k) << 23);
            const bool mc = (mbc >> (s & 63)) & 1ull;
            const float mf = mc ? 1.0f : 0.0f;
            K += mc ? (k + 2) : 0;
            float a[8] = {0.f,0.f,0.f,0.f,0.f,0.f,0.f,0.f};
#pragma unroll
            for (int m = 0; m < 32; ++m) a[m & 7] = dot2(bch2(u[m]), Er[m], a[m & 7]);
            const float p = ((a[0]+a[1])+(a[2]+a[3])) + ((a[4]+a[5])+(a[6]+a[7]));
            const float vn = p * r;
            v = fmaf(mf, vn - v, v);              // mf=0 -> v exactly
            const float y = v * Xc;
            bits_prev = __builtin_amdgcn_readfirstlane(__float_as_int(p));
            const int  yo = __builtin_amdgcn_update_dpp(0, __float_as_int(y), 0xB1, 0xF, 0xF, true);
            pk_i = cvtpk(y, __int_as_float(yo));
            Xc = Xn;
            Xn = eflat[((s - 3) & 63) * NT + j];
        };

        for (int x = NQ - 1; x >= 16; --x) {
            const int gw = (x - 3 >= 16) ? x - 3 : 16;
            write_q(gw);
            const int gl = (x - 4 >= 16) ? x - 4 : 16;
            issue_q(gl);
            if ((x & 3) == 3) {
                mbc = __ballot(mpre != 0);
                const int cn = ((x >> 2) - 1 > 4) ? (x >> 2) - 1 : 4;
                mpre = mask[(cn * 64 + j) * B + b];
            }
            const unsigned qb16 = (unsigned)(mbc >> ((x & 3) << 4)) & 0xFFFFu;
            const int tts = (x == NQ - 1) ? QS - 2 : QS - 1;
            if (qb16 == 0xFFFFu) {
#pragma unroll 1
                for (int tt = tts; tt >= 0; --tt) bstepF(x * QS + tt);
            } else {
#pragma unroll 1
                for (int tt = tts; tt >= 0; --tt) bstepM(x * QS + tt);
            }
        }
        wqb[b * 64 + j] = v;
        if (j == 0) wsb[b] = (float)K * 0.69314718f;

    } else {
        // ======================== numerator wave ============================
        const int b = blockIdx.x - 2 * B;
        float acc = 0.f;
        int   cnt = 0;
#pragma unroll
        for (int m = 0; m < T / 64; ++m) {
            const int t  = j + 64 * m;
            const int mv = mask[t * B + b];
            const int tg = tags[t * B + b];
            cnt += (int)__popcll(__ballot(mv != 0));
            if (t == 0) {
                acc += startT[tg] + emissions[(size_t)b * NT + tg];
            } else if (mv) {
                const int tp = tags[(t - 1) * B + b];
                acc += trans[tp * NT + tg]
                     + emissions[(size_t)(t * B + b) * NT + tg];
            }
        }
#pragma unroll
        for (int off = 32; off > 0; off >>= 1)
            acc += __shfl_xor(acc, off);
        if (j == 0) {
            const int last = tags[(size_t)(cnt - 1) * B + b];
            atomicAdd(out, acc + endT[last]);
        }
    }
}

// den_b = sf + sb + log( sum_j qf_j * qb_j )
__global__ __launch_bounds__(64) void crf_comb(
    const float* __restrict__ wqf, const float* __restrict__ wqb,
    const float* __restrict__ wsf, const float* __restrict__ wsb,
    float* __restrict__ out)
{
    const int b = blockIdx.x;
    const int j = threadIdx.x;
    float v = wqf[b * 64 + j] * wqb[b * 64 + j];
#pragma unroll
    for (int off = 32; off > 0; off >>= 1)
        v += __shfl_xor(v, off);
    if (j == 0)
        atomicAdd(out, -(wsf[b] + wsb[b] + __logf(v)));
}

// ===========================================================================
// Fallback (ws too small): round-3 kernel, verified ~110 us dispatch.
// ===========================================================================
__global__ __launch_bounds__(64) void crf_fused(
    const float* __restrict__ emissions,
    const int*   __restrict__ tags,
    const int*   __restrict__ mask,
    const float* __restrict__ startT,
    const float* __restrict__ endT,
    const float* __restrict__ trans,
    float* __restrict__ out)
{
    const int j = threadIdx.x;
    __shared__ __align__(16) float ebuf[RING][QS][NT];

    if (blockIdx.x < B) {
        const int b = blockIdx.x;
        h2 Eh[NT / 2];
#pragma unroll
        for (int m = 0; m < NT / 2; ++m) {
            Eh[m].x = (_Float16)__expf(trans[(2 * m)     * NT + j]);
            Eh[m].y = (_Float16)__expf(trans[(2 * m + 1) * NT + j]);
        }
        const int jr = j >> 4;
        const int c0 = (j & 15) * 4;
        float4 sA[4];
        auto issue_q = [&](int g) {
#pragma unroll
            for (int k = 0; k < 4; ++k) {
                const int t = g * QS + 4 * k + jr;
                sA[k] = *(const float4*)&emissions[((size_t)t * B + b) * NT + c0];
            }
        };
        auto write_q = [&](int g) {
#pragma unroll
            for (int k = 0; k < 4; ++k) {
                float4 w;
                w.x = __expf(sA[k].x); w.y = __expf(sA[k].y);
                w.z = __expf(sA[k].z); w.w = __expf(sA[k].w);
                *(float4*)&ebuf[g & (RING - 1)][4 * k + jr][c0] = w;
            }
        };
        for (int g = 0; g < 3; ++g) { issue_q(g); write_q(g); }
        issue_q(3);

        const float e0  = emissions[(size_t)b * NT + j];
        const float sc0 = startT[j] + e0;
        const float S0  = rflf(sc0);
        float q = __expf(sc0 - S0);
        int   K = 0;
        int pk_i;
        {
            const int qi = __float_as_int(q);
            const int qo = __builtin_amdgcn_update_dpp(0, qi, 0xB1, 0xF, 0xF, true);
            pk_i = cvtpk(q, __int_as_float(qo));
        }
        float* eflat = &ebuf[0][0][0];
        int bits_prev;
        int mpre = mask[j * B + b];
        unsigned long long mbc = 0;
        {
            int u[32];
#pragma unroll
            for (int m = 0; m < 32; ++m) u[m] = __builtin_amdgcn_readlane(pk_i, 2 * m);
            float a[8] = {0.f,0.f,0.f,0.f,0.f,0.f,0.f,0.f};
#pragma unroll
            for (int m = 0; m < 32; ++m) a[m & 7] = dot2(bch2(u[m]), Eh[m], a[m & 7]);
            const float p = ((a[0]+a[1])+(a[2]+a[3])) + ((a[4]+a[5])+(a[6]+a[7]));
            bits_prev = __builtin_amdgcn_readfirstlane(__float_as_int(p));
            const int  k = ((bits_prev >> 23) & 255) - 127;
            const float r = __int_as_float((125 - k) << 23);
            const float X1 = eflat[NT + j];
            const int  m1 = mask[B + b];
            if (m1) { q = (p * X1) * r; K = k + 2; }
            const int qo = __builtin_amdgcn_update_dpp(0, __float_as_int(q), 0xB1, 0xF, 0xF, true);
            pk_i = cvtpk(q, __int_as_float(qo));
        }
        float Xc = eflat[2 * NT + j];
        float Xn = eflat[3 * NT + j];
        auto stepF = [&](int s) {
            int u[32];
#pragma unroll
            for (int m = 0; m < 32; ++m) u[m] = __builtin_amdgcn_readlane(pk_i, 2 * m);
            __builtin_amdgcn_sched_barrier(0);
            const int  k = ((bits_prev >> 23) & 255) - 127;
            const float r = __int_as_float((125 - k) << 23);
            K += k + 2;
            float a[8] = {0.f,0.f,0.f,0.f,0.f,0.f,0.f,0.f};
#pragma unroll
            for (int m = 0; m < 32; ++m) a[m & 7] = dot2(bch2(u[m]), Eh[m], a[m & 7]);
            const float sXr = Xc * r;
            const float p = ((a[0]+a[1])+(a[2]+a[3])) + ((a[4]+a[5])+(a[6]+a[7]));
            q = p * sXr;
            bits_prev = __builtin_amdgcn_readfirstlane(__float_as_int(p));
            const int qo = __builtin_amdgcn_update_dpp(0, __float_as_int(q), 0xB1, 0xF, 0xF, true);
            pk_i = cvtpk(q, __int_as_float(qo));
            Xc = Xn;
            Xn = eflat[((s + 2) & 63) * NT + j];
        };
        auto stepM = [&](int s) {
            int u[32];
#pragma unroll
            for (int m = 0; m < 32; ++m) u[m] = __builtin_amdgcn_readlane(pk_i, 2 * m);
            __builtin_amdgcn_sched_barrier(0);
            const int  k = ((bits_prev >> 23) & 255) - 127;
            const float r = __int_as_float((125 - k) << 23);
            const bool mc = (mbc >> (s & 63)) & 1ull;
            const float mf = mc ? 1.0f : 0.0f;
            K += mc ? (k + 2) : 0;
            float a[8] = {0.f,0.f,0.f,0.f,0.f,0.f,0.f,0.f};
#pragma unroll
            for (int m = 0; m < 32; ++m) a[m & 7] = dot2(bch2(u[m]), Eh[m], a[m & 7]);
            const float sXr = Xc * r;
            const float p = ((a[0]+a[1])+(a[2]+a[3])) + ((a[4]+a[5])+(a[6]+a[7]));
            const float qn = p * sXr;
            q = fmaf(mf, qn - q, q);
            bits_prev = __builtin_amdgcn_readfirstlane(__float_as_int(p));
            const int qo = __builtin_amdgcn_update_dpp(0, __float_as_int(q), 0xB1, 0xF, 0xF, true);
            pk_i = cvtpk(q, __int_as_float(qo));
            Xc = Xn;
            Xn = eflat[((s + 2) & 63) * NT + j];
        };
        for (int x = 0; x < NQ; ++x) {
            const int gw = (x + 3 < NQ) ? x + 3 : NQ - 1;
            write_q(gw);
            const int gl = (x + 4 < NQ) ? x + 4 : NQ - 1;
            issue_q(gl);
            if ((x & 3) == 0) {
                mbc = __ballot(mpre != 0);
                const int cn = ((x >> 2) + 1 < 8) ? (x >> 2) + 1 : 7;
                mpre = mask[(cn * 64 + j) * B + b];
            }
            const unsigned qb16 = (unsigned)(mbc >> ((x & 3) << 4)) & 0xFFFFu;
            const int tt0 = (x == 0) ? 2 : 0;
            if (qb16 == 0xFFFFu) {
#pragma unroll 1
                for (int tt = tt0; tt < QS; ++tt) stepF(x * QS + tt);
            } else {
#pragma unroll 1
                for (int tt = tt0; tt < QS; ++tt) stepM(x * QS + tt);
            }
        }
        float v = q * __expf(endT[j]);
#pragma unroll
        for (int off = 32; off > 0; off >>= 1) v += __shfl_xor(v, off);
        if (j == 0)
            atomicAdd(out, -(S0 + (float)K * 0.69314718f + __logf(v)));
    } else {
        const int b = blockIdx.x - B;
        float acc = 0.f;
        int   cnt = 0;
#pragma unroll
        for (int m = 0; m < T / 64; ++m) {
            const int t  = j + 64 * m;
            const int mv = mask[t * B + b];
            const int tg = tags[t * B + b];
            cnt += (int)__popcll(__ballot(mv != 0));
            if (t == 0) {
                acc += startT[tg] + emissions[(size_t)b * NT + tg];
            } else if (mv) {
                const int tp = tags[(t - 1) * B + b];
                acc += trans[tp * NT + tg] + emissions[(size_t)(t * B + b) * NT + tg];
            }
        }
#pragma unroll
        for (int off = 32; off > 0; off >>= 1) acc += __shfl_xor(acc, off);
        if (j == 0) {
            const int last = tags[(size_t)(cnt - 1) * B + b];
            atomicAdd(out, acc + endT[last]);
        }
    }
}

extern "C" void kernel_launch(void* const* d_in, const int* in_sizes, int n_in,
                              void* d_out, int out_size, void* d_ws, size_t ws_size,
                              hipStream_t stream) {
    const float* emissions = (const float*)d_in[0];
    const int*   tags      = (const int*)  d_in[1];
    const int*   mask      = (const int*)  d_in[2];
    const float* startT    = (const float*)d_in[3];
    const float* endT      = (const float*)d_in[4];
    const float* trans     = (const float*)d_in[5];
    float* out = (float*)d_out;

    hipMemsetAsync(out, 0, sizeof(float), stream);

    const size_t need = (size_t)(B * 64 * 2 + 2 * B) * sizeof(float); // ~262 KB
    if (d_ws != nullptr && ws_size >= need) {
        float* wqf = (float*)d_ws;
        float* wqb = wqf + B * 64;
        float* wsf = wqb + B * 64;
        float* wsb = wsf + B;
        crf_main<<<3 * B, 64, 0, stream>>>(emissions, tags, mask, startT, endT,
                                           trans, wqf, wqb, wsf, wsb, out);
        crf_comb<<<B, 64, 0, stream>>>(wqf, wqb, wsf, wsb, out);
    } else {
        crf_fused<<<2 * B, 64, 0, stream>>>(emissions, tags, mask, startT,
                                            endT, trans, out);
    }
}